// Round 1
// baseline (325.784 us; speedup 1.0000x reference)
//
#include <hip/hip_runtime.h>
#include <math.h>

#define N 512
#define C 16
#define AGG_IN 1028   // N + (NLAYERS + N), NLAYERS=4

typedef float v4f __attribute__((ext_vector_type(4)));

// Branchless tanh: tanh(x) = sign(x) * (1 - t)/(1 + t), t = exp(-2|x|).
// rel err ~1e-6, far under the 1.98e-2 threshold.
__device__ __forceinline__ float fast_tanh(float x) {
    float ax = fabsf(x);
    float t  = __expf(-2.0f * ax);
    float r  = __fdividef(1.0f - t, 1.0f + t);
    return copysignf(r, x);
}

// Plain cached vector load. (NT dropped: m13's 6.3 TB/s ceiling was measured
// with cached float4 loads; NT bypasses L2/LLC and its throughput is
// uncharacterized on gfx950.)
__device__ __forceinline__ v4f ld4(const float* p) {
    return *(const v4f*)p;
}

// One layer transition, one block per q (512 threads).
// Thread t: channel-quad j = t&3 of edge e = t>>2; 4 passes cover p = 0..511.
// Explicit 1-deep software pipeline: pass n+1's loads (5 fat v4f + per-edge
// scalars + a_in + aW1 column) are issued into a rotating register stage
// BEFORE pass n's compute, keeping ~5.6 KB per wave in flight continuously
// instead of letting the unroller's register pressure sink loads to their uses.
__global__ __launch_bounds__(512, 4) void dan_layer_kernel(
    const float* __restrict__ a_in,    // [N]
    float*       __restrict__ a_out,   // [N]
    const float* __restrict__ vec_W,   // [LT,N,N,C]
    const float* __restrict__ vec_b,   // [LT,N,N,C]
    const float* __restrict__ syn_W1,  // [LT,N,N,3,C]
    const float* __restrict__ syn_b1,  // [LT,N,N,3]
    const float* __restrict__ syn_W2,  // [LT,N,N,3]
    const float* __restrict__ syn_b2,  // [LT,N,N]
    const float* __restrict__ agg_W1,  // [LT,N,3,AGG_IN]
    const float* __restrict__ agg_b1,  // [LT,N,3]
    const float* __restrict__ agg_W2,  // [LT,N,3]
    const float* __restrict__ agg_b2,  // [LT,N]
    int l, int reverse_out)
{
    const int q = blockIdx.x;
    const int t = threadIdx.x;
    const int j = t & 3;        // channel quad
    const int e = t >> 2;       // 0..127 edge slot within pass

    __shared__ float red[3][8];
    __shared__ float hsh[3];

    const size_t qbase = ((size_t)(l * N + q)) * N;   // edge base for p=0
    const int jc = (j < 3) ? j : 2;                    // clamped for aW1 addr
    const float* aW1q = agg_W1 + ((size_t)(l * N + q)) * 3 * AGG_IN + (size_t)jc * AGG_IN;

    float pv = 0.f;   // partial of dot(s[q,:], aW1[k=j,:N]) for j<3

    // ---- stage 0 prefetch (pass 0, p = e) ----
    {
    }
    size_t edge0 = qbase + e;
    v4f w  = ld4(vec_W  + edge0 * C  + j * 4);
    v4f b  = ld4(vec_b  + edge0 * C  + j * 4);
    v4f s0 = ld4(syn_W1 + edge0 * 48 + 0 * C + j * 4);
    v4f s1 = ld4(syn_W1 + edge0 * 48 + 1 * C + j * 4);
    v4f s2 = ld4(syn_W1 + edge0 * 48 + 2 * C + j * 4);
    float av  = a_in[e];
    float b1x = syn_b1[edge0 * 3 + 0];
    float b1y = syn_b1[edge0 * 3 + 1];
    float b1z = syn_b1[edge0 * 3 + 2];
    float w2x = syn_W2[edge0 * 3 + 0];
    float w2y = syn_W2[edge0 * 3 + 1];
    float w2z = syn_W2[edge0 * 3 + 2];
    float bb2 = syn_b2[edge0];
    float aw  = aW1q[e];      // all 4 lanes load (jc clamps j=3 to row 2); j=3 unused

    #pragma unroll
    for (int pass = 0; pass < 4; ++pass) {
        // rotate current stage out of the prefetch registers
        const v4f   cw = w, cb = b, cs0 = s0, cs1 = s1, cs2 = s2;
        const float cav = av;
        const float cb1x = b1x, cb1y = b1y, cb1z = b1z;
        const float cw2x = w2x, cw2y = w2y, cw2z = w2z;
        const float cbb2 = bb2, caw = aw;

        // ---- issue pass n+1's loads before touching pass n's data ----
        if (pass < 3) {
            const int pn = (pass + 1) * 128 + e;
            const size_t en = qbase + pn;
            w  = ld4(vec_W  + en * C  + j * 4);
            b  = ld4(vec_b  + en * C  + j * 4);
            s0 = ld4(syn_W1 + en * 48 + 0 * C + j * 4);
            s1 = ld4(syn_W1 + en * 48 + 1 * C + j * 4);
            s2 = ld4(syn_W1 + en * 48 + 2 * C + j * 4);
            av  = a_in[pn];
            b1x = syn_b1[en * 3 + 0];
            b1y = syn_b1[en * 3 + 1];
            b1z = syn_b1[en * 3 + 2];
            w2x = syn_W2[en * 3 + 0];
            w2y = syn_W2[en * 3 + 1];
            w2z = syn_W2[en * 3 + 2];
            bb2 = syn_b2[en];
            aw  = aW1q[pn];
        }

        // ---- compute pass n ----
        float f0 = fast_tanh(fmaf(cav, cw.x, cb.x));
        float f1 = fast_tanh(fmaf(cav, cw.y, cb.y));
        float f2 = fast_tanh(fmaf(cav, cw.z, cb.z));
        float f3 = fast_tanh(fmaf(cav, cw.w, cb.w));

        float d0 = fmaf(cs0.x, f0, fmaf(cs0.y, f1, fmaf(cs0.z, f2, cs0.w * f3)));
        float d1 = fmaf(cs1.x, f0, fmaf(cs1.y, f1, fmaf(cs1.z, f2, cs1.w * f3)));
        float d2 = fmaf(cs2.x, f0, fmaf(cs2.y, f1, fmaf(cs2.z, f2, cs2.w * f3)));

        // combine the 4 channel-quads of this edge (quad = 4 adjacent lanes)
        d0 += __shfl_xor(d0, 1, 64);  d0 += __shfl_xor(d0, 2, 64);
        d1 += __shfl_xor(d1, 1, 64);  d1 += __shfl_xor(d1, 2, 64);
        d2 += __shfl_xor(d2, 1, 64);  d2 += __shfl_xor(d2, 2, 64);

        // per-edge scalars (already in registers from the prefetch stage)
        float h0 = fast_tanh(d0 + cb1x);
        float h1 = fast_tanh(d1 + cb1y);
        float h2 = fast_tanh(d2 + cb1z);
        float s = cbb2;
        s = fmaf(cw2x, h0, s);
        s = fmaf(cw2y, h1, s);
        s = fmaf(cw2z, h2, s);
        s = fast_tanh(s);

        // aggregator partial: lane j<3 accumulates output k=j for this edge
        if (j < 3) pv = fmaf(s, caw, pv);
    }

    // sum over the 16 edges of this wave (lanes with equal j)
    pv += __shfl_xor(pv, 4, 64);
    pv += __shfl_xor(pv, 8, 64);
    pv += __shfl_xor(pv, 16, 64);
    pv += __shfl_xor(pv, 32, 64);

    const int wave = t >> 6;
    const int lane = t & 63;
    if (lane < 3) red[lane][wave] = pv;   // lanes 0..2 hold j=0..2 sums
    __syncthreads();

    if (t < 3) {
        const int k = t;
        float acc = 0.f;
        #pragma unroll
        for (int w8 = 0; w8 < 8; ++w8) acc += red[k][w8];
        const float* aW1 = agg_W1 + ((size_t)(l * N + q)) * 3 * AGG_IN + (size_t)k * AGG_IN;
        acc += aW1[N + (l + 1)];          // layer one-hot column
        acc += aW1[N + 4 + q];            // node one-hot column
        acc += agg_b1[((size_t)(l * N + q)) * 3 + k];
        hsh[k] = fast_tanh(acc);
    }
    __syncthreads();

    if (t == 0) {
        const float* aW2 = agg_W2 + ((size_t)(l * N + q)) * 3;
        float out = agg_b2[l * N + q];
        out = fmaf(aW2[0], hsh[0], out);
        out = fmaf(aW2[1], hsh[1], out);
        out = fmaf(aW2[2], hsh[2], out);
        if (reverse_out) a_out[N - 1 - q] = out;
        else             a_out[q] = out;
    }
}

extern "C" void kernel_launch(void* const* d_in, const int* in_sizes, int n_in,
                              void* d_out, int out_size, void* d_ws, size_t ws_size,
                              hipStream_t stream) {
    const float* x      = (const float*)d_in[0];
    const float* vec_W  = (const float*)d_in[1];
    const float* vec_b  = (const float*)d_in[2];
    const float* syn_W1 = (const float*)d_in[3];
    const float* syn_b1 = (const float*)d_in[4];
    const float* syn_W2 = (const float*)d_in[5];
    const float* syn_b2 = (const float*)d_in[6];
    const float* agg_W1 = (const float*)d_in[7];
    const float* agg_b1 = (const float*)d_in[8];
    const float* agg_W2 = (const float*)d_in[9];
    const float* agg_b2 = (const float*)d_in[10];
    float* out = (float*)d_out;

    float* a0 = (float*)d_ws;        // [N]
    float* a1 = a0 + N;              // [N]

    dan_layer_kernel<<<N, 512, 0, stream>>>(x,  a0,  vec_W, vec_b, syn_W1, syn_b1,
                                            syn_W2, syn_b2, agg_W1, agg_b1, agg_W2, agg_b2,
                                            0, 0);
    dan_layer_kernel<<<N, 512, 0, stream>>>(a0, a1,  vec_W, vec_b, syn_W1, syn_b1,
                                            syn_W2, syn_b2, agg_W1, agg_b1, agg_W2, agg_b2,
                                            1, 0);
    dan_layer_kernel<<<N, 512, 0, stream>>>(a1, out, vec_W, vec_b, syn_W1, syn_b1,
                                            syn_W2, syn_b2, agg_W1, agg_b1, agg_W2, agg_b2,
                                            2, 1);
}